// Round 1
// baseline (71.082 us; speedup 1.0000x reference)
//
#include <hip/hip_runtime.h>

// Problem constants (from reference)
#define KK 2
#define BB 4
#define VV 2000
#define DD 64
#define HH 4
#define DHH 64
#define PP 128
#define ALPHA_ 0.2f

__device__ __forceinline__ float lrelu(float z) { return z >= 0.f ? z : ALPHA_ * z; }
__device__ __forceinline__ float elu_(float z)  { return z > 0.f ? z : expm1f(z); }

// ---------------------------------------------------------------------------
// Workspace layout (floats):
//   EW  [H][V][DH]   : offset 0          size 512000
//   F1  [H][V]       : offset 512000     size 8000
//   F2  [H][V]       : offset 520000     size 8000
//   LAT [K][B][256]  : offset 528000     size 2048
//   CNT (int)[8]     : offset 530048     size 8
//   S   (int)[K*B][V]: offset 530056     size 16000
// total ~2.2 MB
// ---------------------------------------------------------------------------
#define OFF_EW  0
#define OFF_F1  512000
#define OFF_F2  520000
#define OFF_LAT 528000
#define OFF_CNT 530048
#define OFF_S   530056

// ---- kernel 0: EW[h,v,:] = E[v,:] @ W[h];  F1/F2 = EW . a1/a2 -------------
__global__ __launch_bounds__(256) void k_ew(
    const float* __restrict__ E, const float* __restrict__ W,
    const float* __restrict__ a1, const float* __restrict__ a2,
    float* __restrict__ EW, float* __restrict__ F1, float* __restrict__ F2) {
  const int h = blockIdx.x;
  const int wave = threadIdx.x >> 6, lane = threadIdx.x & 63;
  const int v = blockIdx.y * 4 + wave;
  if (v >= VV) return;
  const float* Wh = W + h * DD * DHH;
  const float* Ev = E + v * DD;
  float acc = 0.f;
#pragma unroll 8
  for (int d = 0; d < DD; ++d) acc = fmaf(Ev[d], Wh[d * DHH + lane], acc);
  EW[(h * VV + v) * DHH + lane] = acc;
  float r1 = acc * a1[h * DHH + lane];
  float r2 = acc * a2[h * DHH + lane];
#pragma unroll
  for (int s = 32; s; s >>= 1) { r1 += __shfl_xor(r1, s); r2 += __shfl_xor(r2, s); }
  if (lane == 0) { F1[h * VV + v] = r1; F2[h * VV + v] = r2; }
}

// ---- kernel 1: deterministic compaction of present nodes; zero LAT --------
__global__ __launch_bounds__(64) void k_compact(
    const float* __restrict__ x, int* __restrict__ S, int* __restrict__ cnt,
    float* __restrict__ lat) {
  const int kb = blockIdx.x;   // k*B + b, 0..7
  const int lane = threadIdx.x;  // 64 threads = 1 wave
  for (int i = lane; i < 256; i += 64) lat[kb * 256 + i] = 0.f;
  const float* xr = x + kb * VV;
  int base = 0;
  for (int t = 0; t * 64 < VV; ++t) {
    const int v = t * 64 + lane;
    const bool f = (v < VV) && (xr[v] > 0.f);
    const unsigned long long m = __ballot(f);
    if (f) {
      const int pos = base + __popcll(m & ((1ull << lane) - 1ull));
      S[kb * VV + pos] = v;
    }
    base += __popcll(m);
  }
  if (lane == 0) cnt[kb] = base;
}

// ---- kernel 2: per present row v: softmax over present u, out = elu(P@EW) -
// one wave handles one (kb, h, row); lane = output dim o (64)
#define WPB 4
__global__ __launch_bounds__(256) void k_attn(
    const float* __restrict__ EW, const float* __restrict__ F1,
    const float* __restrict__ F2, const int* __restrict__ S,
    const int* __restrict__ cnt, float* __restrict__ lat) {
  __shared__ float lds[WPB][2048];  // 32 KB: per-wave p-buffer (n <= 2000)
  const int kb = blockIdx.x;   // 0..7
  const int h = blockIdx.z;    // 0..3
  const int wave = threadIdx.x >> 6, lane = threadIdx.x & 63;
  const int n = cnt[kb];
  const int* Skb = S + kb * VV;
  float* e = lds[wave];
  for (int r = blockIdx.y * WPB + wave; r < n; r += gridDim.y * WPB) {
    const int v = Skb[r];
    const float f1v = F1[h * VV + v];
    // phase A: scores + running max (lanes parallel over u)
    float lmax = -3.4e38f;
    for (int j = lane; j < n; j += 64) {
      float z = lrelu(f1v + F2[h * VV + Skb[j]]);
      e[j] = z;
      lmax = fmaxf(lmax, z);
    }
#pragma unroll
    for (int s = 32; s; s >>= 1) lmax = fmaxf(lmax, __shfl_xor(lmax, s));
    // phase B: p = exp(e - m), sum
    float lsum = 0.f;
    for (int j = lane; j < n; j += 64) {
      const float p = expf(e[j] - lmax);
      e[j] = p;
      lsum += p;
    }
#pragma unroll
    for (int s = 32; s; s >>= 1) lsum += __shfl_xor(lsum, s);
    __builtin_amdgcn_wave_barrier();  // keep compiler from reordering LDS use
    // phase C: out[o] = (sum_j p_j * EW[h, S[j], o]) / sum
    const float inv = 1.f / lsum;
    float acc = 0.f;
    for (int j = 0; j < n; ++j) {
      acc = fmaf(e[j], EW[(h * VV + Skb[j]) * DHH + lane], acc);
    }
    const float o = elu_(acc * inv);
    // lat = max(0, max over rows); only positive values can win vs 0-init
    if (o > 0.f)
      atomicMax(reinterpret_cast<int*>(&lat[kb * 256 + h * DHH + lane]),
                __float_as_int(o));
    __builtin_amdgcn_wave_barrier();
  }
}

// ---- kernel 3: latent pooling + dense head; one block per batch -----------
__global__ __launch_bounds__(256) void k_final(
    const float* __restrict__ cls_w, const float* __restrict__ ac1,
    const float* __restrict__ ac2, const float* __restrict__ dW,
    const float* __restrict__ db, const float* __restrict__ lat,
    float* __restrict__ out) {
  const int b = blockIdx.x;
  const int tid = threadIdx.x;  // 256
  const int lane = tid & 63, wave = tid >> 6;
  __shared__ float pooled[256];
  __shared__ float red[4][4];
  const float cw = cls_w[tid];
  const float l0 = lat[(0 * BB + b) * 256 + tid];
  const float l1 = lat[(1 * BB + b) * 256 + tid];
  float t0 = cw * ac1[tid];
  float t1 = cw * ac2[tid];
  float t2 = l0 * ac2[tid];
  float t3 = l1 * ac2[tid];
#pragma unroll
  for (int s = 32; s; s >>= 1) {
    t0 += __shfl_xor(t0, s); t1 += __shfl_xor(t1, s);
    t2 += __shfl_xor(t2, s); t3 += __shfl_xor(t3, s);
  }
  if (lane == 0) { red[wave][0] = t0; red[wave][1] = t1; red[wave][2] = t2; red[wave][3] = t3; }
  __syncthreads();
  const float ca1 = red[0][0] + red[1][0] + red[2][0] + red[3][0];
  const float d0  = red[0][1] + red[1][1] + red[2][1] + red[3][1];
  const float d1  = red[0][2] + red[1][2] + red[2][2] + red[3][2];
  const float d2  = red[0][3] + red[1][3] + red[2][3] + red[3][3];
  const float e0 = lrelu(ca1 + d0), e1 = lrelu(ca1 + d1), e2 = lrelu(ca1 + d2);
  const float m = fmaxf(e0, fmaxf(e1, e2));
  const float x0 = expf(e0 - m), x1 = expf(e1 - m), x2 = expf(e2 - m);
  const float invs = 1.f / (x0 + x1 + x2);
  const float w0 = x0 * invs, w1 = x1 * invs, w2 = x2 * invs;
  pooled[tid] = w0 * cw + w1 * l0 + w2 * l1;
  __syncthreads();
  if (tid < PP) {
    float acc = db[tid];
    for (int f = 0; f < 256; ++f) acc = fmaf(pooled[f], dW[f * PP + tid], acc);
    out[b * PP + tid] = elu_(acc);
  }
}

extern "C" void kernel_launch(void* const* d_in, const int* in_sizes, int n_in,
                              void* d_out, int out_size, void* d_ws, size_t ws_size,
                              hipStream_t stream) {
  const float* x     = (const float*)d_in[0];
  const float* E     = (const float*)d_in[1];
  const float* W     = (const float*)d_in[2];
  const float* a1    = (const float*)d_in[3];
  const float* a2    = (const float*)d_in[4];
  const float* cls_w = (const float*)d_in[5];
  const float* ac1   = (const float*)d_in[6];
  const float* ac2   = (const float*)d_in[7];
  const float* dW    = (const float*)d_in[8];
  const float* db    = (const float*)d_in[9];
  float* out = (float*)d_out;

  float* ws  = (float*)d_ws;
  float* EW  = ws + OFF_EW;
  float* F1  = ws + OFF_F1;
  float* F2  = ws + OFF_F2;
  float* LAT = ws + OFF_LAT;
  int*   CNT = (int*)(ws + OFF_CNT);
  int*   S   = (int*)(ws + OFF_S);

  k_ew<<<dim3(HH, (VV + 3) / 4), 256, 0, stream>>>(E, W, a1, a2, EW, F1, F2);
  k_compact<<<KK * BB, 64, 0, stream>>>(x, S, CNT, LAT);
  k_attn<<<dim3(KK * BB, 64, HH), 256, 0, stream>>>(EW, F1, F2, S, CNT, LAT);
  k_final<<<BB, 256, 0, stream>>>(cls_w, ac1, ac2, dW, db, LAT, out);
}

// Round 2
// 60.145 us; speedup vs baseline: 1.1818x; 1.1818x over previous
//
#include <hip/hip_runtime.h>

// Problem constants (from reference)
#define KK 2
#define BB 4
#define VV 2000
#define DD 64
#define HH 4
#define DHH 64
#define PP 128
#define ALPHA_ 0.2f

__device__ __forceinline__ float lrelu(float z) { return z >= 0.f ? z : ALPHA_ * z; }
__device__ __forceinline__ float elu_(float z)  { return z > 0.f ? z : expm1f(z); }

// ---------------------------------------------------------------------------
// Workspace layout (floats):
//   EW  [H][V][DH]   : offset 0          size 512000
//   F1  [H][V]       : offset 512000     size 8000
//   F2  [H][V]       : offset 520000     size 8000
//   LAT [K][B][256]  : offset 528000     size 2048
//   CNT (int)[8]     : offset 530048     size 8
//   S   (int)[K*B][V]: offset 530056     size 16000
// ---------------------------------------------------------------------------
#define OFF_EW  0
#define OFF_F1  512000
#define OFF_F2  520000
#define OFF_LAT 528000
#define OFF_CNT 530048
#define OFF_S   530056

// ---- kernel 0 (fused): EW/F1/F2 precompute + present-set compaction -------
// blocks [0, 2000): EW — h = bid&3, v-group = bid>>2 (4 rows per block)
// blocks [2000, 2008): compaction for kb = bid-2000 (wave 0 only)
__global__ __launch_bounds__(256) void k_pre(
    const float* __restrict__ E, const float* __restrict__ W,
    const float* __restrict__ a1, const float* __restrict__ a2,
    const float* __restrict__ x,
    float* __restrict__ EW, float* __restrict__ F1, float* __restrict__ F2,
    int* __restrict__ S, int* __restrict__ cnt, float* __restrict__ lat) {
  const int bid = blockIdx.x;
  const int wave = threadIdx.x >> 6, lane = threadIdx.x & 63;
  if (bid < 2000) {
    const int h = bid & 3;
    const int v = (bid >> 2) * 4 + wave;
    const float* Wh = W + h * DD * DHH;
    const float* Ev = E + v * DD;
    float acc = 0.f;
#pragma unroll 8
    for (int d = 0; d < DD; ++d) acc = fmaf(Ev[d], Wh[d * DHH + lane], acc);
    EW[(h * VV + v) * DHH + lane] = acc;
    float r1 = acc * a1[h * DHH + lane];
    float r2 = acc * a2[h * DHH + lane];
#pragma unroll
    for (int s = 32; s; s >>= 1) { r1 += __shfl_xor(r1, s); r2 += __shfl_xor(r2, s); }
    if (lane == 0) { F1[h * VV + v] = r1; F2[h * VV + v] = r2; }
  } else {
    if (wave != 0) return;
    const int kb = bid - 2000;  // 0..7
    for (int i = lane; i < 256; i += 64) lat[kb * 256 + i] = 0.f;
    const float* xr = x + kb * VV;
    int base = 0;
    for (int t = 0; t * 64 < VV; ++t) {
      const int v = t * 64 + lane;
      const bool f = (v < VV) && (xr[v] > 0.f);
      const unsigned long long m = __ballot(f);
      if (f) {
        const int pos = base + __popcll(m & ((1ull << lane) - 1ull));
        S[kb * VV + pos] = v;
      }
      base += __popcll(m);
    }
    if (lane == 0) cnt[kb] = base;
  }
}

// ---- kernel 1: per present row v: softmax over present u, out = elu(P@EW) -
// one wave per (kb, h, row); lane = output dim o. Indices + gathered F2
// staged in LDS per block; phase C unrolled x8 with 4 accumulators.
#define WPB 4
__global__ __launch_bounds__(256) void k_attn(
    const float* __restrict__ EW, const float* __restrict__ F1,
    const float* __restrict__ F2, const int* __restrict__ S,
    const int* __restrict__ cnt, float* __restrict__ lat) {
  __shared__ float e_[WPB][2048];  // 32 KB: per-wave p-buffer (n <= 2000)
  __shared__ int   Sl[2048];       // 8 KB: compacted indices (block-shared)
  __shared__ float G2l[2048];      // 8 KB: gathered F2 (block-shared)
  const int kb = blockIdx.x;   // 0..7
  const int h = blockIdx.z;    // 0..3
  const int wave = threadIdx.x >> 6, lane = threadIdx.x & 63;
  const int n = cnt[kb];
  if (blockIdx.y * WPB >= n) return;  // later rows are handled by small-y blocks
  const int* Skb = S + kb * VV;
  const float* F2h = F2 + h * VV;
  const float* F1h = F1 + h * VV;
  // block-cooperative staging of indices + gathered F2
  for (int j = threadIdx.x; j < n; j += 256) {
    const int v = Skb[j];
    Sl[j] = v;
    G2l[j] = F2h[v];
  }
  __syncthreads();
  float* e = e_[wave];
  const float* EWh = EW + (size_t)h * VV * DHH + lane;
  for (int r = blockIdx.y * WPB + wave; r < n; r += gridDim.y * WPB) {
    const float f1v = F1h[Sl[r]];
    // phase A: scores + running max (lanes parallel over u)
    float lmax = -3.4e38f;
    for (int j = lane; j < n; j += 64) {
      const float z = lrelu(f1v + G2l[j]);
      e[j] = z;
      lmax = fmaxf(lmax, z);
    }
#pragma unroll
    for (int s = 32; s; s >>= 1) lmax = fmaxf(lmax, __shfl_xor(lmax, s));
    // phase B: p = exp(e - m), sum
    float lsum = 0.f;
    for (int j = lane; j < n; j += 64) {
      const float p = expf(e[j] - lmax);
      e[j] = p;
      lsum += p;
    }
#pragma unroll
    for (int s = 32; s; s >>= 1) lsum += __shfl_xor(lsum, s);
    __builtin_amdgcn_wave_barrier();
    // phase C: out[o] = (sum_j p_j * EW[h, S[j], o]) / sum  — unrolled x8
    float a0 = 0.f, a1v = 0.f, a2v = 0.f, a3v = 0.f;
    int j = 0;
    for (; j + 8 <= n; j += 8) {
      const int4   i03 = *reinterpret_cast<const int4*>(&Sl[j]);
      const int4   i47 = *reinterpret_cast<const int4*>(&Sl[j + 4]);
      const float4 q03 = *reinterpret_cast<const float4*>(&e[j]);
      const float4 q47 = *reinterpret_cast<const float4*>(&e[j + 4]);
      const float v0 = EWh[(size_t)i03.x * DHH];
      const float v1 = EWh[(size_t)i03.y * DHH];
      const float v2 = EWh[(size_t)i03.z * DHH];
      const float v3 = EWh[(size_t)i03.w * DHH];
      const float v4 = EWh[(size_t)i47.x * DHH];
      const float v5 = EWh[(size_t)i47.y * DHH];
      const float v6 = EWh[(size_t)i47.z * DHH];
      const float v7 = EWh[(size_t)i47.w * DHH];
      a0 = fmaf(q03.x, v0, a0);
      a1v = fmaf(q03.y, v1, a1v);
      a2v = fmaf(q03.z, v2, a2v);
      a3v = fmaf(q03.w, v3, a3v);
      a0 = fmaf(q47.x, v4, a0);
      a1v = fmaf(q47.y, v5, a1v);
      a2v = fmaf(q47.z, v6, a2v);
      a3v = fmaf(q47.w, v7, a3v);
    }
    for (; j < n; ++j) a0 = fmaf(e[j], EWh[(size_t)Sl[j] * DHH], a0);
    const float acc = (a0 + a1v) + (a2v + a3v);
    const float o = elu_(acc / lsum);
    // lat = max(0, max over rows); only positive values can win vs 0-init
    if (o > 0.f)
      atomicMax(reinterpret_cast<int*>(&lat[kb * 256 + h * DHH + lane]),
                __float_as_int(o));
    __builtin_amdgcn_wave_barrier();
  }
}

// ---- kernel 2: latent pooling + dense head; one block per batch -----------
__global__ __launch_bounds__(256) void k_final(
    const float* __restrict__ cls_w, const float* __restrict__ ac1,
    const float* __restrict__ ac2, const float* __restrict__ dW,
    const float* __restrict__ db, const float* __restrict__ lat,
    float* __restrict__ out) {
  const int b = blockIdx.x;
  const int tid = threadIdx.x;  // 256
  const int lane = tid & 63, wave = tid >> 6;
  __shared__ float pooled[256];
  __shared__ float red[4][4];
  const float cw = cls_w[tid];
  const float l0 = lat[(0 * BB + b) * 256 + tid];
  const float l1 = lat[(1 * BB + b) * 256 + tid];
  float t0 = cw * ac1[tid];
  float t1 = cw * ac2[tid];
  float t2 = l0 * ac2[tid];
  float t3 = l1 * ac2[tid];
#pragma unroll
  for (int s = 32; s; s >>= 1) {
    t0 += __shfl_xor(t0, s); t1 += __shfl_xor(t1, s);
    t2 += __shfl_xor(t2, s); t3 += __shfl_xor(t3, s);
  }
  if (lane == 0) { red[wave][0] = t0; red[wave][1] = t1; red[wave][2] = t2; red[wave][3] = t3; }
  __syncthreads();
  const float ca1 = red[0][0] + red[1][0] + red[2][0] + red[3][0];
  const float d0  = red[0][1] + red[1][1] + red[2][1] + red[3][1];
  const float d1  = red[0][2] + red[1][2] + red[2][2] + red[3][2];
  const float d2  = red[0][3] + red[1][3] + red[2][3] + red[3][3];
  const float e0 = lrelu(ca1 + d0), e1 = lrelu(ca1 + d1), e2 = lrelu(ca1 + d2);
  const float m = fmaxf(e0, fmaxf(e1, e2));
  const float x0 = expf(e0 - m), x1 = expf(e1 - m), x2 = expf(e2 - m);
  const float invs = 1.f / (x0 + x1 + x2);
  const float w0 = x0 * invs, w1 = x1 * invs, w2 = x2 * invs;
  pooled[tid] = w0 * cw + w1 * l0 + w2 * l1;
  __syncthreads();
  if (tid < PP) {
    float acc = db[tid];
    for (int f = 0; f < 256; ++f) acc = fmaf(pooled[f], dW[f * PP + tid], acc);
    out[b * PP + tid] = elu_(acc);
  }
}

extern "C" void kernel_launch(void* const* d_in, const int* in_sizes, int n_in,
                              void* d_out, int out_size, void* d_ws, size_t ws_size,
                              hipStream_t stream) {
  const float* x     = (const float*)d_in[0];
  const float* E     = (const float*)d_in[1];
  const float* W     = (const float*)d_in[2];
  const float* a1    = (const float*)d_in[3];
  const float* a2    = (const float*)d_in[4];
  const float* cls_w = (const float*)d_in[5];
  const float* ac1   = (const float*)d_in[6];
  const float* ac2   = (const float*)d_in[7];
  const float* dW    = (const float*)d_in[8];
  const float* db    = (const float*)d_in[9];
  float* out = (float*)d_out;

  float* ws  = (float*)d_ws;
  float* EW  = ws + OFF_EW;
  float* F1  = ws + OFF_F1;
  float* F2  = ws + OFF_F2;
  float* LAT = ws + OFF_LAT;
  int*   CNT = (int*)(ws + OFF_CNT);
  int*   S   = (int*)(ws + OFF_S);

  k_pre<<<2000 + KK * BB, 256, 0, stream>>>(E, W, a1, a2, x, EW, F1, F2, S, CNT, LAT);
  k_attn<<<dim3(KK * BB, 64, HH), 256, 0, stream>>>(EW, F1, F2, S, CNT, LAT);
  k_final<<<BB, 256, 0, stream>>>(cls_w, ac1, ac2, dW, db, LAT, out);
}

// Round 3
// 45.898 us; speedup vs baseline: 1.5487x; 1.3104x over previous
//
#include <hip/hip_runtime.h>

// Problem constants (from reference)
#define KK 2
#define BB 4
#define VV 2000
#define DD 64
#define HH 4
#define DHH 64
#define PP 128
#define ALPHA_ 0.2f

__device__ __forceinline__ float lrelu(float z) { return z >= 0.f ? z : ALPHA_ * z; }
__device__ __forceinline__ float elu_(float z)  { return z > 0.f ? z : expm1f(z); }

// ---------------------------------------------------------------------------
// Workspace layout (floats):
//   EW  [H][V][DH]   : offset 0          size 512000
//   F1  [H][V]       : offset 512000     size 8000
//   F2  [H][V]       : offset 520000     size 8000
//   LAT [K][B][256]  : offset 528000     size 2048
//   CNT (int)[8]     : offset 530048     size 8
//   S   (int)[K*B][V]: offset 530056     size 16000
// ---------------------------------------------------------------------------
#define OFF_EW  0
#define OFF_F1  512000
#define OFF_F2  520000
#define OFF_LAT 528000
#define OFF_CNT 530048
#define OFF_S   530056

// ---- kernel 0 (fused): EW/F1/F2 precompute + present-set compaction -------
// blocks [0, 2000): EW — h = bid/500 (h-major: consecutive blocks share W_h
//                   in L1), 4 v-rows per block (one per wave)
// blocks [2000, 2008): compaction for kb = bid-2000 (wave 0 only)
__global__ __launch_bounds__(256) void k_pre(
    const float* __restrict__ E, const float* __restrict__ W,
    const float* __restrict__ a1, const float* __restrict__ a2,
    const float* __restrict__ x,
    float* __restrict__ EW, float* __restrict__ F1, float* __restrict__ F2,
    int* __restrict__ S, int* __restrict__ cnt, float* __restrict__ lat) {
  const int bid = blockIdx.x;
  const int wave = threadIdx.x >> 6, lane = threadIdx.x & 63;
  if (bid < 2000) {
    const int h = bid / 500;
    const int v = (bid % 500) * 4 + wave;
    const float* Wh = W + h * DD * DHH;
    const float* Ev = E + v * DD;
    float acc = 0.f;
#pragma unroll 8
    for (int d = 0; d < DD; ++d) acc = fmaf(Ev[d], Wh[d * DHH + lane], acc);
    EW[(h * VV + v) * DHH + lane] = acc;
    float r1 = acc * a1[h * DHH + lane];
    float r2 = acc * a2[h * DHH + lane];
#pragma unroll
    for (int s = 32; s; s >>= 1) { r1 += __shfl_xor(r1, s); r2 += __shfl_xor(r2, s); }
    if (lane == 0) { F1[h * VV + v] = r1; F2[h * VV + v] = r2; }
  } else {
    if (wave != 0) return;
    const int kb = bid - 2000;  // 0..7
    for (int i = lane; i < 256; i += 64) lat[kb * 256 + i] = 0.f;
    const float* xr = x + kb * VV;
    int base = 0;
    for (int t = 0; t * 64 < VV; ++t) {
      const int v = t * 64 + lane;
      const bool f = (v < VV) && (xr[v] > 0.f);
      const unsigned long long m = __ballot(f);
      if (f) {
        const int pos = base + __popcll(m & ((1ull << lane) - 1ull));
        S[kb * VV + pos] = v;
      }
      base += __popcll(m);
    }
    if (lane == 0) cnt[kb] = base;
  }
}

// ---- kernel 1: attention rows, LDS-staged ---------------------------------
// block = (kb, 32-row tile, h); 4 waves x 8 rows each; lane = output dim o.
// Gathered EW rows staged in LDS in chunks of KT and shared by all 32 rows.
#define RPW 8                 // rows per wave
#define NWV 4                 // waves per block
#define RPB (RPW * NWV)       // 32 rows per block
#define KT  128               // source rows per LDS chunk

__global__ __launch_bounds__(256) void k_attn(
    const float* __restrict__ EW, const float* __restrict__ F1,
    const float* __restrict__ F2, const int* __restrict__ S,
    const int* __restrict__ cnt, float* __restrict__ lat) {
  __shared__ float EWg[KT][DHH];        // 32 KB gathered EW chunk
  __shared__ float G2l[2048];           // 8 KB  gathered F2 (full present set)
  __shared__ float pT[NWV][KT][RPW];    // 16 KB transposed probs per wave
  const int kb = blockIdx.x;            // 0..7
  const int h = blockIdx.z;             // 0..3
  const int tid = threadIdx.x;
  const int wave = tid >> 6, lane = tid & 63;
  const int n = cnt[kb];
  const int y0 = blockIdx.y * RPB;
  if (y0 >= n) return;                  // idle tile (uniform across block)
  const int* Skb = S + kb * VV;
  const float* F2h = F2 + h * VV;
  const float* F1h = F1 + h * VV;
  const float* EWh = EW + (size_t)h * VV * DHH;

  // stage gathered F2 for the whole present set
  for (int j = tid; j < n; j += 256) G2l[j] = F2h[Skb[j]];

  // own-row metadata
  const int r0 = y0 + wave * RPW;
  bool act[RPW]; float f1r[RPW];
#pragma unroll
  for (int i = 0; i < RPW; ++i) {
    const int r = r0 + i;
    act[i] = r < n;
    f1r[i] = F1h[Skb[act[i] ? r : 0]];
  }
  __syncthreads();

  // pass A: per-row max (8 rows jointly, lanes parallel over j)
  float m[RPW];
#pragma unroll
  for (int i = 0; i < RPW; ++i) m[i] = -3.4e38f;
  for (int jb = lane; jb < n; jb += 64) {
    const float g = G2l[jb];
#pragma unroll
    for (int i = 0; i < RPW; ++i) m[i] = fmaxf(m[i], lrelu(f1r[i] + g));
  }
#pragma unroll
  for (int s = 32; s; s >>= 1)
#pragma unroll
    for (int i = 0; i < RPW; ++i) m[i] = fmaxf(m[i], __shfl_xor(m[i], s));

  // pass B: per-row sum
  float sm[RPW];
#pragma unroll
  for (int i = 0; i < RPW; ++i) sm[i] = 0.f;
  for (int jb = lane; jb < n; jb += 64) {
    const float g = G2l[jb];
#pragma unroll
    for (int i = 0; i < RPW; ++i) sm[i] += expf(lrelu(f1r[i] + g) - m[i]);
  }
#pragma unroll
  for (int s = 32; s; s >>= 1)
#pragma unroll
    for (int i = 0; i < RPW; ++i) sm[i] += __shfl_xor(sm[i], s);
  float inv[RPW];
#pragma unroll
  for (int i = 0; i < RPW; ++i) inv[i] = 1.f / sm[i];

  // phase C: chunked PV accumulate out of LDS
  float acc[RPW];
#pragma unroll
  for (int i = 0; i < RPW; ++i) acc[i] = 0.f;
  for (int jc = 0; jc < n; jc += KT) {
    const int L = (n - jc < KT) ? (n - jc) : KT;
    __syncthreads();  // previous chunk fully consumed
    // block-cooperative stage of gathered EW rows [jc, jc+L)
    for (int t = tid; t < L * 16; t += 256) {
      const int jj = t >> 4, c = (t & 15) << 2;
      const int v = Skb[jc + jj];
      *reinterpret_cast<float4*>(&EWg[jj][c]) =
          *reinterpret_cast<const float4*>(&EWh[(size_t)v * DHH + c]);
    }
    // per-wave: normalized probs for own 8 rows, transposed layout
    for (int jb = lane; jb < L; jb += 64) {
      const float g = G2l[jc + jb];
      float4 pa, pb;
      pa.x = expf(lrelu(f1r[0] + g) - m[0]) * inv[0];
      pa.y = expf(lrelu(f1r[1] + g) - m[1]) * inv[1];
      pa.z = expf(lrelu(f1r[2] + g) - m[2]) * inv[2];
      pa.w = expf(lrelu(f1r[3] + g) - m[3]) * inv[3];
      pb.x = expf(lrelu(f1r[4] + g) - m[4]) * inv[4];
      pb.y = expf(lrelu(f1r[5] + g) - m[5]) * inv[5];
      pb.z = expf(lrelu(f1r[6] + g) - m[6]) * inv[6];
      pb.w = expf(lrelu(f1r[7] + g) - m[7]) * inv[7];
      *reinterpret_cast<float4*>(&pT[wave][jb][0]) = pa;
      *reinterpret_cast<float4*>(&pT[wave][jb][4]) = pb;
    }
    __syncthreads();
    // hot loop: 1 conflict-free ds_read + 2 broadcast float4 + 8 fma per j
    for (int jj = 0; jj < L; ++jj) {
      const float v = EWg[jj][lane];
      const float4 pa = *reinterpret_cast<const float4*>(&pT[wave][jj][0]);
      const float4 pb = *reinterpret_cast<const float4*>(&pT[wave][jj][4]);
      acc[0] = fmaf(pa.x, v, acc[0]);
      acc[1] = fmaf(pa.y, v, acc[1]);
      acc[2] = fmaf(pa.z, v, acc[2]);
      acc[3] = fmaf(pa.w, v, acc[3]);
      acc[4] = fmaf(pb.x, v, acc[4]);
      acc[5] = fmaf(pb.y, v, acc[5]);
      acc[6] = fmaf(pb.z, v, acc[6]);
      acc[7] = fmaf(pb.w, v, acc[7]);
    }
  }

  // epilogue: elu + positive-only atomic max into lat
  int* latp = reinterpret_cast<int*>(&lat[kb * 256 + h * DHH + lane]);
#pragma unroll
  for (int i = 0; i < RPW; ++i) {
    if (act[i]) {
      const float o = elu_(acc[i]);
      if (o > 0.f) atomicMax(latp, __float_as_int(o));
    }
  }
}

// ---- kernel 2: latent pooling + dense head; one block per batch -----------
__global__ __launch_bounds__(256) void k_final(
    const float* __restrict__ cls_w, const float* __restrict__ ac1,
    const float* __restrict__ ac2, const float* __restrict__ dW,
    const float* __restrict__ db, const float* __restrict__ lat,
    float* __restrict__ out) {
  const int b = blockIdx.x;
  const int tid = threadIdx.x;  // 256
  const int lane = tid & 63, wave = tid >> 6;
  __shared__ float pooled[256];
  __shared__ float red[4][4];
  const float cw = cls_w[tid];
  const float l0 = lat[(0 * BB + b) * 256 + tid];
  const float l1 = lat[(1 * BB + b) * 256 + tid];
  float t0 = cw * ac1[tid];
  float t1 = cw * ac2[tid];
  float t2 = l0 * ac2[tid];
  float t3 = l1 * ac2[tid];
#pragma unroll
  for (int s = 32; s; s >>= 1) {
    t0 += __shfl_xor(t0, s); t1 += __shfl_xor(t1, s);
    t2 += __shfl_xor(t2, s); t3 += __shfl_xor(t3, s);
  }
  if (lane == 0) { red[wave][0] = t0; red[wave][1] = t1; red[wave][2] = t2; red[wave][3] = t3; }
  __syncthreads();
  const float ca1 = red[0][0] + red[1][0] + red[2][0] + red[3][0];
  const float d0  = red[0][1] + red[1][1] + red[2][1] + red[3][1];
  const float d1  = red[0][2] + red[1][2] + red[2][2] + red[3][2];
  const float d2  = red[0][3] + red[1][3] + red[2][3] + red[3][3];
  const float e0 = lrelu(ca1 + d0), e1 = lrelu(ca1 + d1), e2 = lrelu(ca1 + d2);
  const float mm = fmaxf(e0, fmaxf(e1, e2));
  const float x0 = expf(e0 - mm), x1 = expf(e1 - mm), x2 = expf(e2 - mm);
  const float invs = 1.f / (x0 + x1 + x2);
  const float w0 = x0 * invs, w1 = x1 * invs, w2 = x2 * invs;
  pooled[tid] = w0 * cw + w1 * l0 + w2 * l1;
  __syncthreads();
  if (tid < PP) {
    float acc = db[tid];
    for (int f = 0; f < 256; ++f) acc = fmaf(pooled[f], dW[f * PP + tid], acc);
    out[b * PP + tid] = elu_(acc);
  }
}

extern "C" void kernel_launch(void* const* d_in, const int* in_sizes, int n_in,
                              void* d_out, int out_size, void* d_ws, size_t ws_size,
                              hipStream_t stream) {
  const float* x     = (const float*)d_in[0];
  const float* E     = (const float*)d_in[1];
  const float* W     = (const float*)d_in[2];
  const float* a1    = (const float*)d_in[3];
  const float* a2    = (const float*)d_in[4];
  const float* cls_w = (const float*)d_in[5];
  const float* ac1   = (const float*)d_in[6];
  const float* ac2   = (const float*)d_in[7];
  const float* dW    = (const float*)d_in[8];
  const float* db    = (const float*)d_in[9];
  float* out = (float*)d_out;

  float* ws  = (float*)d_ws;
  float* EW  = ws + OFF_EW;
  float* F1  = ws + OFF_F1;
  float* F2  = ws + OFF_F2;
  float* LAT = ws + OFF_LAT;
  int*   CNT = (int*)(ws + OFF_CNT);
  int*   S   = (int*)(ws + OFF_S);

  k_pre<<<2000 + KK * BB, 256, 0, stream>>>(E, W, a1, a2, x, EW, F1, F2, S, CNT, LAT);
  k_attn<<<dim3(KK * BB, (VV + RPB - 1) / RPB, HH), 256, 0, stream>>>(EW, F1, F2, S, CNT, LAT);
  k_final<<<BB, 256, 0, stream>>>(cls_w, ac1, ac2, dW, db, LAT, out);
}